// Round 9
// baseline (346.575 us; speedup 1.0000x reference)
//
#include <hip/hip_runtime.h>

#define N_NODES 50000
#define N_EDGES 800000
#define N_GRAPHS 256
#define SCAN_B ((N_NODES + 255) / 256)
#define FILL_GROUPS 8
#define NPG (N_NODES / FILL_GROUPS)   // 6250 nodes per group

typedef __attribute__((ext_vector_type(8))) short bf16x8;
typedef __attribute__((ext_vector_type(4))) float f32x4;

__device__ inline unsigned short f2bf(float f) {
    unsigned int u = __float_as_uint(f);
    u += 0x7fff + ((u >> 16) & 1);          // RNE
    return (unsigned short)(u >> 16);
}
__device__ inline float bf2f(unsigned short h) {
    return __uint_as_float(((unsigned int)h) << 16);
}
__device__ inline float fast_tanh(float x) {
    return 1.0f - 2.0f / (__expf(2.0f * x) + 1.0f);
}

// ---------------------------------------------------------------------------
// weight pre-split: fp32 -> packed bf16 hi/lo, concatenated [128][KTOT]
// ---------------------------------------------------------------------------
__global__ void pack_w_kernel(const float* __restrict__ s0, const float* __restrict__ s1,
                              int K0, int KTOT, int nconcat,
                              unsigned short* __restrict__ hi, unsigned short* __restrict__ lo)
{
    const int idx = blockIdx.x * 256 + threadIdx.x;
    if (idx >= 128 * KTOT) return;
    const int c = idx / KTOT, k = idx % KTOT;
    float v;
    if (nconcat) v = (c < 64) ? s0[c * KTOT + k] : s1[(c - 64) * KTOT + k];
    else         v = (k < K0) ? s0[c * K0 + k]   : s1[c * K0 + (k - K0)];
    const unsigned short h = f2bf(v);
    hi[idx] = h;
    lo[idx] = f2bf(v - bf2f(h));
}

// ---------------------------------------------------------------------------
// fp32 -> bf16 convert (vectorized)
// ---------------------------------------------------------------------------
__global__ void cvt_bf16_kernel(const float* __restrict__ in,
                                unsigned short* __restrict__ out, int n4)
{
    const int i = blockIdx.x * 256 + threadIdx.x;
    if (i >= n4) return;
    const float4 v = ((const float4*)in)[i];
    ((ushort4*)out)[i] = make_ushort4(f2bf(v.x), f2bf(v.y), f2bf(v.z), f2bf(v.w));
}

// ---------------------------------------------------------------------------
// MFMA GEMM, mixed A chunks (fp32 on-the-fly split / exact bf16)
// ---------------------------------------------------------------------------
template<int KF32, int KB16, bool OUTSPLIT, bool ACT>
__global__ __launch_bounds__(256)
void gemm_mfma(const float* __restrict__ Af, int fstr,
               const unsigned short* __restrict__ Ab, int bstr,
               const unsigned short* __restrict__ Bhi, const unsigned short* __restrict__ Blo,
               const float* __restrict__ bias,
               unsigned short* __restrict__ C16, float* __restrict__ Cf)
{
    constexpr int KTOT = KF32 + KB16;
    constexpr int NCHF = KF32 / 32;
    constexpr int NCH  = KTOT / 32;

    __shared__ __align__(16) unsigned short lah[64 * 40];
    __shared__ __align__(16) unsigned short lal[64 * 40];
    __shared__ __align__(16) unsigned short lbh[128 * 40];
    __shared__ __align__(16) unsigned short lbl[128 * 40];

    const int tid = threadIdx.x;
    const int w = tid >> 6;
    const int lane = tid & 63;
    const int lrow = lane & 15;
    const int lkb = lane >> 4;
    const int m0 = blockIdx.x * 64;

    f32x4 acc[4][2] = {};

    for (int ch = 0; ch < NCH; ++ch) {
        const bool isF = (ch < NCHF);
        const int bk0 = ch * 32;

        __syncthreads();
        if (isF) {
            const int ak0 = ch * 32;
#pragma unroll
            for (int p = 0; p < 2; ++p) {
                const int f = tid + p * 256;
                const int r = f >> 3;
                const int q = f & 7;
                int row = m0 + r; if (row >= N_NODES) row = N_NODES - 1;
                const float4 v = *(const float4*)&Af[(long)row * fstr + ak0 + q * 4];
                const unsigned short h0 = f2bf(v.x), h1 = f2bf(v.y), h2 = f2bf(v.z), h3 = f2bf(v.w);
                *(ushort4*)&lah[r * 40 + q * 4] = make_ushort4(h0, h1, h2, h3);
                *(ushort4*)&lal[r * 40 + q * 4] =
                    make_ushort4(f2bf(v.x - bf2f(h0)), f2bf(v.y - bf2f(h1)),
                                 f2bf(v.z - bf2f(h2)), f2bf(v.w - bf2f(h3)));
            }
        } else {
            const int ak0 = (ch - NCHF) * 32;
            const int r = tid >> 2;
            const int q = tid & 3;
            int row = m0 + r; if (row >= N_NODES) row = N_NODES - 1;
            *(uint4*)&lah[r * 40 + q * 8] = *(const uint4*)&Ab[(long)row * bstr + ak0 + q * 8];
        }
#pragma unroll
        for (int p = 0; p < 2; ++p) {
            const int f = tid + p * 256;
            const int r = f >> 2;
            const int q = f & 3;
            const long g = (long)r * KTOT + bk0 + q * 8;
            *(uint4*)&lbh[r * 40 + q * 8] = *(const uint4*)&Bhi[g];
            *(uint4*)&lbl[r * 40 + q * 8] = *(const uint4*)&Blo[g];
        }
        __syncthreads();

        const int bo0 = (w * 32 + lrow) * 40 + lkb * 8;
        const int bo1 = bo0 + 16 * 40;
        const bf16x8 bh0 = *(const bf16x8*)&lbh[bo0];
        const bf16x8 bh1 = *(const bf16x8*)&lbh[bo1];
        const bf16x8 bl0 = *(const bf16x8*)&lbl[bo0];
        const bf16x8 bl1 = *(const bf16x8*)&lbl[bo1];
#pragma unroll
        for (int m = 0; m < 4; ++m) {
            const int ao = (m * 16 + lrow) * 40 + lkb * 8;
            const bf16x8 ah = *(const bf16x8*)&lah[ao];
            acc[m][0] = __builtin_amdgcn_mfma_f32_16x16x32_bf16(ah, bh0, acc[m][0], 0, 0, 0);
            acc[m][1] = __builtin_amdgcn_mfma_f32_16x16x32_bf16(ah, bh1, acc[m][1], 0, 0, 0);
            acc[m][0] = __builtin_amdgcn_mfma_f32_16x16x32_bf16(ah, bl0, acc[m][0], 0, 0, 0);
            acc[m][1] = __builtin_amdgcn_mfma_f32_16x16x32_bf16(ah, bl1, acc[m][1], 0, 0, 0);
            if (isF) {
                const bf16x8 al = *(const bf16x8*)&lal[ao];
                acc[m][0] = __builtin_amdgcn_mfma_f32_16x16x32_bf16(al, bh0, acc[m][0], 0, 0, 0);
                acc[m][1] = __builtin_amdgcn_mfma_f32_16x16x32_bf16(al, bh1, acc[m][1], 0, 0, 0);
            }
        }
    }

    const int c0 = w * 32 + lrow;
    if (!OUTSPLIT) {
        const float bb0 = bias[c0], bb1 = bias[c0 + 16];
#pragma unroll
        for (int m = 0; m < 4; ++m) {
#pragma unroll
            for (int r = 0; r < 4; ++r) {
                const int row = m0 + m * 16 + lkb * 4 + r;
                if (row < N_NODES) {
                    float v0 = acc[m][0][r] + bb0;
                    float v1 = acc[m][1][r] + bb1;
                    if (ACT) { v0 = fast_tanh(v0); v1 = fast_tanh(v1); }
                    C16[(long)row * 128 + c0]      = f2bf(v0);
                    C16[(long)row * 128 + c0 + 16] = f2bf(v1);
                }
            }
        }
    } else if (c0 < 64) {
#pragma unroll
        for (int m = 0; m < 4; ++m) {
#pragma unroll
            for (int r = 0; r < 4; ++r) {
                const int row = m0 + m * 16 + lkb * 4 + r;
                if (row < N_NODES) {
                    C16[(long)row * 64 + c0]      = f2bf(acc[m][0][r]);
                    C16[(long)row * 64 + c0 + 16] = f2bf(acc[m][1][r]);
                }
            }
        }
    } else {
        const float bb0 = bias[c0 - 64], bb1 = bias[c0 - 48];
#pragma unroll
        for (int m = 0; m < 4; ++m) {
#pragma unroll
            for (int r = 0; r < 4; ++r) {
                const int row = m0 + m * 16 + lkb * 4 + r;
                if (row < N_NODES) {
                    Cf[(long)row * 64 + c0 - 64] = acc[m][0][r] + bb0;
                    Cf[(long)row * 64 + c0 - 48] = acc[m][1][r] + bb1;
                }
            }
        }
    }
}

// ---------------------------------------------------------------------------
// CSR build: count -> hierarchical scan -> XCD-localized fill
// ---------------------------------------------------------------------------
__global__ void count_kernel(const int* __restrict__ ei, int* __restrict__ count)
{
    const int e = blockIdx.x * blockDim.x + threadIdx.x;
    if (e < N_EDGES) atomicAdd(&count[ei[N_EDGES + e]], 1);
}

__global__ __launch_bounds__(256)
void scan_blocks_kernel(const int* __restrict__ count, int* __restrict__ blocksum)
{
    __shared__ int red[256];
    const int i = blockIdx.x * 256 + threadIdx.x;
    red[threadIdx.x] = (i < N_NODES) ? count[i] : 0;
    __syncthreads();
#pragma unroll
    for (int d = 128; d > 0; d >>= 1) {
        if (threadIdx.x < d) red[threadIdx.x] += red[threadIdx.x + d];
        __syncthreads();
    }
    if (threadIdx.x == 0) blocksum[blockIdx.x] = red[0];
}

__global__ __launch_bounds__(256)
void scan_base_kernel(const int* __restrict__ blocksum, int* __restrict__ blockbase)
{
    __shared__ int s[256];
    const int t = threadIdx.x;
    const int own = (t < SCAN_B) ? blocksum[t] : 0;
    s[t] = own;
    __syncthreads();
#pragma unroll
    for (int d = 1; d < 256; d <<= 1) {
        const int v = (t >= d) ? s[t - d] : 0;
        __syncthreads();
        s[t] += v;
        __syncthreads();
    }
    if (t < SCAN_B) blockbase[t] = s[t] - own;
}

__global__ __launch_bounds__(256)
void scan_final_kernel(const int* __restrict__ count, const int* __restrict__ blockbase,
                       int* __restrict__ offsets, int* __restrict__ cursor)
{
    __shared__ int s[256];
    const int t = threadIdx.x;
    const int i = blockIdx.x * 256 + t;
    const int v = (i < N_NODES) ? count[i] : 0;
    s[t] = v;
    __syncthreads();
#pragma unroll
    for (int d = 1; d < 256; d <<= 1) {
        const int u = (t >= d) ? s[t - d] : 0;
        __syncthreads();
        s[t] += u;
        __syncthreads();
    }
    if (i < N_NODES) {
        const int off = blockbase[blockIdx.x] + s[t] - v;
        offsets[i] = off;
        cursor[i] = off;
    }
    if (i == 0) offsets[N_NODES] = N_EDGES;
}

__global__ __launch_bounds__(256)
void fill_kernel(const int* __restrict__ ei, const float* __restrict__ ew,
                 int* __restrict__ cursor, uint2* __restrict__ rec)
{
    const int g = blockIdx.x & (FILL_GROUPS - 1);
    const int q = blockIdx.x >> 3;
    const int nlo = g * NPG;
    const int nhi = nlo + NPG;
    const int stride = (gridDim.x >> 3) * 256;
    for (int e = q * 256 + threadIdx.x; e < N_EDGES; e += stride) {
        const int t = ei[N_EDGES + e];
        if (t >= nlo && t < nhi) {
            const int pos = atomicAdd(&cursor[t], 1);
            rec[pos] = make_uint2((unsigned)ei[e], __float_as_uint(ew[e]));
        }
    }
}

// ---------------------------------------------------------------------------
// column-pass gather: agg[n][colbase..colbase+32) = sum_e w_e * feat[src_e][cols]
// per pass the touched feature bytes = N * 64B = 3.2 MB -> fits per-XCD L2.
// 4 lanes per node (8 cols = 16B each), 64 nodes per block, fp32 accumulate.
// ---------------------------------------------------------------------------
__global__ __launch_bounds__(256)
void gather_pass(const unsigned short* __restrict__ feat, int stride, int colbase,
                 const int* __restrict__ offsets, const uint2* __restrict__ rec,
                 float* __restrict__ agg, int dstr)
{
    const int lane = threadIdx.x & 3;
    const int slot = threadIdx.x >> 2;
    const int n = blockIdx.x * 64 + slot;
    if (n >= N_NODES) return;
    const int lo = offsets[n], hi = offsets[n + 1];
    const int j = colbase + lane * 8;
    float a0[8] = {}, a1[8] = {};
    int e = lo;
    for (; e + 1 < hi; e += 2) {
        const uint2 r0 = rec[e];
        const uint2 r1 = rec[e + 1];
        const bf16x8 v0 = *(const bf16x8*)&feat[(long)r0.x * stride + j];
        const bf16x8 v1 = *(const bf16x8*)&feat[(long)r1.x * stride + j];
        const float w0 = __uint_as_float(r0.y);
        const float w1 = __uint_as_float(r1.y);
#pragma unroll
        for (int k = 0; k < 8; ++k) {
            a0[k] = fmaf(bf2f((unsigned short)v0[k]), w0, a0[k]);
            a1[k] = fmaf(bf2f((unsigned short)v1[k]), w1, a1[k]);
        }
    }
    if (e < hi) {
        const uint2 r = rec[e];
        const bf16x8 v = *(const bf16x8*)&feat[(long)r.x * stride + j];
        const float w = __uint_as_float(r.y);
#pragma unroll
        for (int k = 0; k < 8; ++k)
            a0[k] = fmaf(bf2f((unsigned short)v[k]), w, a0[k]);
    }
    *(float4*)&agg[(long)n * dstr + j] =
        make_float4(a0[0] + a1[0], a0[1] + a1[1], a0[2] + a1[2], a0[3] + a1[3]);
    *(float4*)&agg[(long)n * dstr + j + 4] =
        make_float4(a0[4] + a1[4], a0[5] + a1[5], a0[6] + a1[6], a0[7] + a1[7]);
}

// ---------------------------------------------------------------------------
// pool + MLP
// ---------------------------------------------------------------------------
__global__ void gstart_kernel(const int* __restrict__ batch, int* __restrict__ gstart)
{
    const int g = threadIdx.x;
    int lo = 0, hi = N_NODES;
    while (lo < hi) { const int mid = (lo + hi) >> 1; if (batch[mid] < g) lo = mid + 1; else hi = mid; }
    gstart[g] = lo;
    if (g == 0) gstart[N_GRAPHS] = N_NODES;
}

__global__ __launch_bounds__(256)
void pool_seg_kernel(const float* __restrict__ agg3, const float* __restrict__ root3,
                     const int* __restrict__ gstart, float* __restrict__ g)
{
    const int gi = blockIdx.x;
    const int c = threadIdx.x & 63;
    const int sub = threadIdx.x >> 6;
    const int lo = gstart[gi], hi = gstart[gi + 1];
    float acc = 0.f;
    for (int n = lo + sub; n < hi; n += 4)
        acc += fast_tanh(agg3[(long)n * 64 + c] + root3[(long)n * 64 + c]);
    __shared__ float red[256];
    red[threadIdx.x] = acc;
    __syncthreads();
    if (sub == 0) g[gi * 64 + c] = red[c] + red[64 + c] + red[128 + c] + red[192 + c];
}

__global__ __launch_bounds__(64)
void mlp_kernel(const float* __restrict__ g,
                const float* __restrict__ Wm1, const float* __restrict__ bm1,
                const float* __restrict__ Wm2, const float* __restrict__ bm2,
                const float* __restrict__ Wm3, const float* __restrict__ bm3,
                float* __restrict__ out)
{
    const int gi = blockIdx.x;
    const int l = threadIdx.x;
    __shared__ float gr[64], h1[32], h2[16];
    gr[l] = g[gi * 64 + l];
    __syncthreads();
    if (l < 32) {
        float a = bm1[l];
        const float* w = Wm1 + l * 64;
        for (int k = 0; k < 64; ++k) a = fmaf(gr[k], w[k], a);
        h1[l] = fmaxf(a, 0.f);
    }
    __syncthreads();
    if (l < 16) {
        float a = bm2[l];
        const float* w = Wm2 + l * 32;
        for (int k = 0; k < 32; ++k) a = fmaf(h1[k], w[k], a);
        h2[l] = fmaxf(a, 0.f);
    }
    __syncthreads();
    if (l == 0) {
        float a = bm3[0];
        for (int k = 0; k < 16; ++k) a = fmaf(h2[k], Wm3[k], a);
        out[gi] = a;
    }
}

extern "C" void kernel_launch(void* const* d_in, const int* in_sizes, int n_in,
                              void* d_out, int out_size, void* d_ws, size_t ws_size,
                              hipStream_t stream) {
    const float* x      = (const float*)d_in[0];
    const int*   ei     = (const int*)  d_in[1];
    const int*   batch  = (const int*)  d_in[2];
    const float* ew     = (const float*)d_in[3];
    const float* W1r    = (const float*)d_in[4];
    const float* b1     = (const float*)d_in[5];
    const float* W1root = (const float*)d_in[6];
    const float* W2r    = (const float*)d_in[7];
    const float* b2     = (const float*)d_in[8];
    const float* W2root = (const float*)d_in[9];
    const float* W3r    = (const float*)d_in[10];
    const float* b3     = (const float*)d_in[11];
    const float* W3root = (const float*)d_in[12];
    const float* Wm1    = (const float*)d_in[13];
    const float* bm1    = (const float*)d_in[14];
    const float* Wm2    = (const float*)d_in[15];
    const float* bm2    = (const float*)d_in[16];
    const float* Wm3    = (const float*)d_in[17];
    const float* bm3    = (const float*)d_in[18];
    float* out = (float*)d_out;

    // ---- workspace layout ----
    float* agg1  = (float*)d_ws;                        // N*64 f32 (reused as agg3)
    float* agg2  = agg1 + (long)N_NODES * 64;           // N*128 f32 (reused: y3b + root3)
    float* POOL  = agg2 + (long)N_NODES * 128;          // 256*64
    int*   count    = (int*)(POOL + N_GRAPHS * 64);
    int*   offsets  = count + N_NODES;                  // N+1
    int*   cursor   = offsets + N_NODES + 1;            // N+1
    int*   gstart   = cursor + N_NODES + 1;             // 257
    int*   blocksum = gstart + N_GRAPHS + 1;            // SCAN_B
    int*   blockbase= blocksum + SCAN_B;                // SCAN_B
    uintptr_t wp = ((uintptr_t)(blockbase + SCAN_B) + 15) & ~(uintptr_t)15;
    uint2* rec = (uint2*)wp;                            // E * 8B
    unsigned short* xb  = (unsigned short*)(rec + N_EDGES);  // N*64 bf16
    unsigned short* h1b = xb + (long)N_NODES * 64;           // N*128 bf16
    unsigned short* h2b = h1b + (long)N_NODES * 128;         // N*128 bf16
    unsigned short* Bh1 = h2b + (long)N_NODES * 128;         // 128*128
    unsigned short* Bl1 = Bh1 + 128 * 128;
    unsigned short* Bh2 = Bl1 + 128 * 128;                   // 128*256
    unsigned short* Bl2 = Bh2 + 128 * 256;
    unsigned short* Bh3 = Bl2 + 128 * 256;                   // 128*128
    unsigned short* Bl3 = Bh3 + 128 * 128;
    // layer-3 outputs carved from agg2 region (free after GEMM2):
    unsigned short* y3b = (unsigned short*)agg2;             // N*64 bf16
    float* root3 = agg2 + (long)N_NODES * 64;                // N*64 f32
    float* agg3  = agg1;                                     // N*64 f32

    const int gemm_grid = (N_NODES + 63) / 64;    // 782
    const int gat_grid  = (N_NODES + 63) / 64;    // 782
    const int egrid = (N_EDGES + 255) / 256;

    // ---- weight pre-split + x->bf16 ----
    pack_w_kernel<<<(128 * 128 + 255) / 256, 256, 0, stream>>>(W1r, W1root, 64, 128, 0, Bh1, Bl1);
    pack_w_kernel<<<(128 * 256 + 255) / 256, 256, 0, stream>>>(W2r, W2root, 128, 256, 0, Bh2, Bl2);
    pack_w_kernel<<<(128 * 128 + 255) / 256, 256, 0, stream>>>(W3r, W3root, 128, 128, 1, Bh3, Bl3);
    cvt_bf16_kernel<<<(N_NODES * 64 / 4 + 255) / 256, 256, 0, stream>>>(x, xb, N_NODES * 64 / 4);

    // ---- CSR build ----
    hipMemsetAsync(count, 0, N_NODES * sizeof(int), stream);
    count_kernel<<<egrid, 256, 0, stream>>>(ei, count);
    scan_blocks_kernel<<<SCAN_B, 256, 0, stream>>>(count, blocksum);
    scan_base_kernel<<<1, 256, 0, stream>>>(blocksum, blockbase);
    scan_final_kernel<<<SCAN_B, 256, 0, stream>>>(count, blockbase, offsets, cursor);
    fill_kernel<<<2048, 256, 0, stream>>>(ei, ew, cursor, rec);
    gstart_kernel<<<1, 256, 0, stream>>>(batch, gstart);

    // ---- layer 1: agg1 = gather(xb) [2 col passes]; h1b = bf16(tanh([agg1|xb]@B1+b1))
    gather_pass<<<gat_grid, 256, 0, stream>>>(xb, 64, 0,  offsets, rec, agg1, 64);
    gather_pass<<<gat_grid, 256, 0, stream>>>(xb, 64, 32, offsets, rec, agg1, 64);
    gemm_mfma<64, 64, false, true><<<gemm_grid, 256, 0, stream>>>(
        agg1, 64, xb, 64, Bh1, Bl1, b1, h1b, nullptr);

    // ---- layer 2: agg2 = gather(h1b) [4 col passes]; h2b = ... ----
    gather_pass<<<gat_grid, 256, 0, stream>>>(h1b, 128, 0,  offsets, rec, agg2, 128);
    gather_pass<<<gat_grid, 256, 0, stream>>>(h1b, 128, 32, offsets, rec, agg2, 128);
    gather_pass<<<gat_grid, 256, 0, stream>>>(h1b, 128, 64, offsets, rec, agg2, 128);
    gather_pass<<<gat_grid, 256, 0, stream>>>(h1b, 128, 96, offsets, rec, agg2, 128);
    gemm_mfma<128, 128, false, true><<<gemm_grid, 256, 0, stream>>>(
        agg2, 128, h1b, 128, Bh2, Bl2, b2, h2b, nullptr);

    // ---- layer 3: y3b = bf16(h2b@W3r^T); root3 = h2b@W3root^T + b3 ----
    gemm_mfma<0, 128, true, false><<<gemm_grid, 256, 0, stream>>>(
        nullptr, 0, h2b, 128, Bh3, Bl3, b3, y3b, root3);
    gather_pass<<<gat_grid, 256, 0, stream>>>(y3b, 64, 0,  offsets, rec, agg3, 64);
    gather_pass<<<gat_grid, 256, 0, stream>>>(y3b, 64, 32, offsets, rec, agg3, 64);

    // ---- pool + MLP ----
    pool_seg_kernel<<<N_GRAPHS, 256, 0, stream>>>(agg3, root3, gstart, POOL);
    mlp_kernel<<<N_GRAPHS, 64, 0, stream>>>(POOL, Wm1, bm1, Wm2, bm2, Wm3, bm3, out);
}

// Round 11
// 302.290 us; speedup vs baseline: 1.1465x; 1.1465x over previous
//
#include <hip/hip_runtime.h>

#define N_NODES 50000
#define N_EDGES 800000
#define N_GRAPHS 256
#define SCAN_B ((N_NODES + 255) / 256)
#define FILL_GROUPS 8
#define NPG (N_NODES / FILL_GROUPS)   // 6250 nodes per group

typedef __attribute__((ext_vector_type(8))) short bf16x8;
typedef __attribute__((ext_vector_type(4))) float f32x4;

__device__ inline unsigned short f2bf(float f) {
    unsigned int u = __float_as_uint(f);
    u += 0x7fff + ((u >> 16) & 1);          // RNE
    return (unsigned short)(u >> 16);
}
__device__ inline float bf2f(unsigned short h) {
    return __uint_as_float(((unsigned int)h) << 16);
}
__device__ inline float fast_tanh(float x) {
    return 1.0f - 2.0f / (__expf(2.0f * x) + 1.0f);
}

// ---------------------------------------------------------------------------
// weight pre-split: fp32 -> packed bf16 hi/lo, concatenated [128][KTOT]
// ---------------------------------------------------------------------------
__global__ void pack_w_kernel(const float* __restrict__ s0, const float* __restrict__ s1,
                              int K0, int KTOT, int nconcat,
                              unsigned short* __restrict__ hi, unsigned short* __restrict__ lo)
{
    const int idx = blockIdx.x * 256 + threadIdx.x;
    if (idx >= 128 * KTOT) return;
    const int c = idx / KTOT, k = idx % KTOT;
    float v;
    if (nconcat) v = (c < 64) ? s0[c * KTOT + k] : s1[(c - 64) * KTOT + k];
    else         v = (k < K0) ? s0[c * K0 + k]   : s1[c * K0 + (k - K0)];
    const unsigned short h = f2bf(v);
    hi[idx] = h;
    lo[idx] = f2bf(v - bf2f(h));
}

// ---------------------------------------------------------------------------
// fp32 -> bf16 convert (vectorized)
// ---------------------------------------------------------------------------
__global__ void cvt_bf16_kernel(const float* __restrict__ in,
                                unsigned short* __restrict__ out, int n4)
{
    const int i = blockIdx.x * 256 + threadIdx.x;
    if (i >= n4) return;
    const float4 v = ((const float4*)in)[i];
    ((ushort4*)out)[i] = make_ushort4(f2bf(v.x), f2bf(v.y), f2bf(v.z), f2bf(v.w));
}

// ---------------------------------------------------------------------------
// MFMA GEMM, mixed A chunks (fp32 on-the-fly split / exact bf16)
// ---------------------------------------------------------------------------
template<int KF32, int KB16, bool OUTSPLIT, bool ACT>
__global__ __launch_bounds__(256)
void gemm_mfma(const float* __restrict__ Af, int fstr,
               const unsigned short* __restrict__ Ab, int bstr,
               const unsigned short* __restrict__ Bhi, const unsigned short* __restrict__ Blo,
               const float* __restrict__ bias,
               unsigned short* __restrict__ C16, float* __restrict__ Cf)
{
    constexpr int KTOT = KF32 + KB16;
    constexpr int NCHF = KF32 / 32;
    constexpr int NCH  = KTOT / 32;

    __shared__ __align__(16) unsigned short lah[64 * 40];
    __shared__ __align__(16) unsigned short lal[64 * 40];
    __shared__ __align__(16) unsigned short lbh[128 * 40];
    __shared__ __align__(16) unsigned short lbl[128 * 40];

    const int tid = threadIdx.x;
    const int w = tid >> 6;
    const int lane = tid & 63;
    const int lrow = lane & 15;
    const int lkb = lane >> 4;
    const int m0 = blockIdx.x * 64;

    f32x4 acc[4][2] = {};

    for (int ch = 0; ch < NCH; ++ch) {
        const bool isF = (ch < NCHF);
        const int bk0 = ch * 32;

        __syncthreads();
        if (isF) {
            const int ak0 = ch * 32;
#pragma unroll
            for (int p = 0; p < 2; ++p) {
                const int f = tid + p * 256;
                const int r = f >> 3;
                const int q = f & 7;
                int row = m0 + r; if (row >= N_NODES) row = N_NODES - 1;
                const float4 v = *(const float4*)&Af[(long)row * fstr + ak0 + q * 4];
                const unsigned short h0 = f2bf(v.x), h1 = f2bf(v.y), h2 = f2bf(v.z), h3 = f2bf(v.w);
                *(ushort4*)&lah[r * 40 + q * 4] = make_ushort4(h0, h1, h2, h3);
                *(ushort4*)&lal[r * 40 + q * 4] =
                    make_ushort4(f2bf(v.x - bf2f(h0)), f2bf(v.y - bf2f(h1)),
                                 f2bf(v.z - bf2f(h2)), f2bf(v.w - bf2f(h3)));
            }
        } else {
            const int ak0 = (ch - NCHF) * 32;
            const int r = tid >> 2;
            const int q = tid & 3;
            int row = m0 + r; if (row >= N_NODES) row = N_NODES - 1;
            *(uint4*)&lah[r * 40 + q * 8] = *(const uint4*)&Ab[(long)row * bstr + ak0 + q * 8];
        }
#pragma unroll
        for (int p = 0; p < 2; ++p) {
            const int f = tid + p * 256;
            const int r = f >> 2;
            const int q = f & 3;
            const long g = (long)r * KTOT + bk0 + q * 8;
            *(uint4*)&lbh[r * 40 + q * 8] = *(const uint4*)&Bhi[g];
            *(uint4*)&lbl[r * 40 + q * 8] = *(const uint4*)&Blo[g];
        }
        __syncthreads();

        const int bo0 = (w * 32 + lrow) * 40 + lkb * 8;
        const int bo1 = bo0 + 16 * 40;
        const bf16x8 bh0 = *(const bf16x8*)&lbh[bo0];
        const bf16x8 bh1 = *(const bf16x8*)&lbh[bo1];
        const bf16x8 bl0 = *(const bf16x8*)&lbl[bo0];
        const bf16x8 bl1 = *(const bf16x8*)&lbl[bo1];
#pragma unroll
        for (int m = 0; m < 4; ++m) {
            const int ao = (m * 16 + lrow) * 40 + lkb * 8;
            const bf16x8 ah = *(const bf16x8*)&lah[ao];
            acc[m][0] = __builtin_amdgcn_mfma_f32_16x16x32_bf16(ah, bh0, acc[m][0], 0, 0, 0);
            acc[m][1] = __builtin_amdgcn_mfma_f32_16x16x32_bf16(ah, bh1, acc[m][1], 0, 0, 0);
            acc[m][0] = __builtin_amdgcn_mfma_f32_16x16x32_bf16(ah, bl0, acc[m][0], 0, 0, 0);
            acc[m][1] = __builtin_amdgcn_mfma_f32_16x16x32_bf16(ah, bl1, acc[m][1], 0, 0, 0);
            if (isF) {
                const bf16x8 al = *(const bf16x8*)&lal[ao];
                acc[m][0] = __builtin_amdgcn_mfma_f32_16x16x32_bf16(al, bh0, acc[m][0], 0, 0, 0);
                acc[m][1] = __builtin_amdgcn_mfma_f32_16x16x32_bf16(al, bh1, acc[m][1], 0, 0, 0);
            }
        }
    }

    const int c0 = w * 32 + lrow;
    if (!OUTSPLIT) {
        const float bb0 = bias[c0], bb1 = bias[c0 + 16];
#pragma unroll
        for (int m = 0; m < 4; ++m) {
#pragma unroll
            for (int r = 0; r < 4; ++r) {
                const int row = m0 + m * 16 + lkb * 4 + r;
                if (row < N_NODES) {
                    float v0 = acc[m][0][r] + bb0;
                    float v1 = acc[m][1][r] + bb1;
                    if (ACT) { v0 = fast_tanh(v0); v1 = fast_tanh(v1); }
                    C16[(long)row * 128 + c0]      = f2bf(v0);
                    C16[(long)row * 128 + c0 + 16] = f2bf(v1);
                }
            }
        }
    } else if (c0 < 64) {
#pragma unroll
        for (int m = 0; m < 4; ++m) {
#pragma unroll
            for (int r = 0; r < 4; ++r) {
                const int row = m0 + m * 16 + lkb * 4 + r;
                if (row < N_NODES) {
                    C16[(long)row * 64 + c0]      = f2bf(acc[m][0][r]);
                    C16[(long)row * 64 + c0 + 16] = f2bf(acc[m][1][r]);
                }
            }
        }
    } else {
        const float bb0 = bias[c0 - 64], bb1 = bias[c0 - 48];
#pragma unroll
        for (int m = 0; m < 4; ++m) {
#pragma unroll
            for (int r = 0; r < 4; ++r) {
                const int row = m0 + m * 16 + lkb * 4 + r;
                if (row < N_NODES) {
                    Cf[(long)row * 64 + c0 - 64] = acc[m][0][r] + bb0;
                    Cf[(long)row * 64 + c0 - 48] = acc[m][1][r] + bb1;
                }
            }
        }
    }
}

// ---------------------------------------------------------------------------
// CSR build: count -> hierarchical scan -> XCD-localized fill
// ---------------------------------------------------------------------------
__global__ void count_kernel(const int* __restrict__ ei, int* __restrict__ count)
{
    const int e = blockIdx.x * blockDim.x + threadIdx.x;
    if (e < N_EDGES) atomicAdd(&count[ei[N_EDGES + e]], 1);
}

__global__ __launch_bounds__(256)
void scan_blocks_kernel(const int* __restrict__ count, int* __restrict__ blocksum)
{
    __shared__ int red[256];
    const int i = blockIdx.x * 256 + threadIdx.x;
    red[threadIdx.x] = (i < N_NODES) ? count[i] : 0;
    __syncthreads();
#pragma unroll
    for (int d = 128; d > 0; d >>= 1) {
        if (threadIdx.x < d) red[threadIdx.x] += red[threadIdx.x + d];
        __syncthreads();
    }
    if (threadIdx.x == 0) blocksum[blockIdx.x] = red[0];
}

__global__ __launch_bounds__(256)
void scan_base_kernel(const int* __restrict__ blocksum, int* __restrict__ blockbase)
{
    __shared__ int s[256];
    const int t = threadIdx.x;
    const int own = (t < SCAN_B) ? blocksum[t] : 0;
    s[t] = own;
    __syncthreads();
#pragma unroll
    for (int d = 1; d < 256; d <<= 1) {
        const int v = (t >= d) ? s[t - d] : 0;
        __syncthreads();
        s[t] += v;
        __syncthreads();
    }
    if (t < SCAN_B) blockbase[t] = s[t] - own;
}

__global__ __launch_bounds__(256)
void scan_final_kernel(const int* __restrict__ count, const int* __restrict__ blockbase,
                       int* __restrict__ offsets, int* __restrict__ cursor)
{
    __shared__ int s[256];
    const int t = threadIdx.x;
    const int i = blockIdx.x * 256 + t;
    const int v = (i < N_NODES) ? count[i] : 0;
    s[t] = v;
    __syncthreads();
#pragma unroll
    for (int d = 1; d < 256; d <<= 1) {
        const int u = (t >= d) ? s[t - d] : 0;
        __syncthreads();
        s[t] += u;
        __syncthreads();
    }
    if (i < N_NODES) {
        const int off = blockbase[blockIdx.x] + s[t] - v;
        offsets[i] = off;
        cursor[i] = off;
    }
    if (i == 0) offsets[N_NODES] = N_EDGES;
}

// XCD-localized fill; rec stores nontemporal (written once, streamed)
__global__ __launch_bounds__(256)
void fill_kernel(const int* __restrict__ ei, const float* __restrict__ ew,
                 int* __restrict__ cursor, unsigned long long* __restrict__ rec)
{
    const int g = blockIdx.x & (FILL_GROUPS - 1);
    const int q = blockIdx.x >> 3;
    const int nlo = g * NPG;
    const int nhi = nlo + NPG;
    const int stride = (gridDim.x >> 3) * 256;
    for (int e = q * 256 + threadIdx.x; e < N_EDGES; e += stride) {
        const int t = ei[N_EDGES + e];
        if (t >= nlo && t < nhi) {
            const int pos = atomicAdd(&cursor[t], 1);
            const unsigned long long v =
                ((unsigned long long)__float_as_uint(ew[e]) << 32) | (unsigned)ei[e];
            __builtin_nontemporal_store(v, &rec[pos]);
        }
    }
}

// ---------------------------------------------------------------------------
// gather aggregation over bf16 features, fp32 accumulate. D/8 lanes per node.
// rec loads + agg stores nontemporal (streams) -> keep L2 for feat lines.
// ---------------------------------------------------------------------------
template<int D>
__global__ __launch_bounds__(256)
void gather_agg(const unsigned short* __restrict__ feat, int stride,
                const int* __restrict__ offsets, const unsigned long long* __restrict__ rec,
                float* __restrict__ agg)
{
    constexpr int LPN = D / 8;
    constexpr int NPB = 256 / LPN;
    const int lane = threadIdx.x % LPN;
    const int slot = threadIdx.x / LPN;
    const int n = blockIdx.x * NPB + slot;
    if (n >= N_NODES) return;
    const int lo = offsets[n], hi = offsets[n + 1];
    const int j = lane * 8;
    float a0[8] = {}, a1[8] = {};
    int e = lo;
    for (; e + 1 < hi; e += 2) {
        const unsigned long long r0 = __builtin_nontemporal_load(&rec[e]);
        const unsigned long long r1 = __builtin_nontemporal_load(&rec[e + 1]);
        const bf16x8 v0 = *(const bf16x8*)&feat[(long)(unsigned)r0 * stride + j];
        const bf16x8 v1 = *(const bf16x8*)&feat[(long)(unsigned)r1 * stride + j];
        const float w0 = __uint_as_float((unsigned)(r0 >> 32));
        const float w1 = __uint_as_float((unsigned)(r1 >> 32));
#pragma unroll
        for (int k = 0; k < 8; ++k) {
            a0[k] = fmaf(bf2f((unsigned short)v0[k]), w0, a0[k]);
            a1[k] = fmaf(bf2f((unsigned short)v1[k]), w1, a1[k]);
        }
    }
    if (e < hi) {
        const unsigned long long r = __builtin_nontemporal_load(&rec[e]);
        const bf16x8 v = *(const bf16x8*)&feat[(long)(unsigned)r * stride + j];
        const float w = __uint_as_float((unsigned)(r >> 32));
#pragma unroll
        for (int k = 0; k < 8; ++k)
            a0[k] = fmaf(bf2f((unsigned short)v[k]), w, a0[k]);
    }
    f32x4 o0 = { a0[0] + a1[0], a0[1] + a1[1], a0[2] + a1[2], a0[3] + a1[3] };
    f32x4 o1 = { a0[4] + a1[4], a0[5] + a1[5], a0[6] + a1[6], a0[7] + a1[7] };
    __builtin_nontemporal_store(o0, (f32x4*)&agg[(long)n * D + j]);
    __builtin_nontemporal_store(o1, (f32x4*)&agg[(long)n * D + j + 4]);
}

// ---------------------------------------------------------------------------
// pool + MLP
// ---------------------------------------------------------------------------
__global__ void gstart_kernel(const int* __restrict__ batch, int* __restrict__ gstart)
{
    const int g = threadIdx.x;
    int lo = 0, hi = N_NODES;
    while (lo < hi) { const int mid = (lo + hi) >> 1; if (batch[mid] < g) lo = mid + 1; else hi = mid; }
    gstart[g] = lo;
    if (g == 0) gstart[N_GRAPHS] = N_NODES;
}

__global__ __launch_bounds__(256)
void pool_seg_kernel(const float* __restrict__ agg3, const float* __restrict__ root3,
                     const int* __restrict__ gstart, float* __restrict__ g)
{
    const int gi = blockIdx.x;
    const int c = threadIdx.x & 63;
    const int sub = threadIdx.x >> 6;
    const int lo = gstart[gi], hi = gstart[gi + 1];
    float acc = 0.f;
    for (int n = lo + sub; n < hi; n += 4)
        acc += fast_tanh(agg3[(long)n * 64 + c] + root3[(long)n * 64 + c]);
    __shared__ float red[256];
    red[threadIdx.x] = acc;
    __syncthreads();
    if (sub == 0) g[gi * 64 + c] = red[c] + red[64 + c] + red[128 + c] + red[192 + c];
}

__global__ __launch_bounds__(64)
void mlp_kernel(const float* __restrict__ g,
                const float* __restrict__ Wm1, const float* __restrict__ bm1,
                const float* __restrict__ Wm2, const float* __restrict__ bm2,
                const float* __restrict__ Wm3, const float* __restrict__ bm3,
                float* __restrict__ out)
{
    const int gi = blockIdx.x;
    const int l = threadIdx.x;
    __shared__ float gr[64], h1[32], h2[16];
    gr[l] = g[gi * 64 + l];
    __syncthreads();
    if (l < 32) {
        float a = bm1[l];
        const float* w = Wm1 + l * 64;
        for (int k = 0; k < 64; ++k) a = fmaf(gr[k], w[k], a);
        h1[l] = fmaxf(a, 0.f);
    }
    __syncthreads();
    if (l < 16) {
        float a = bm2[l];
        const float* w = Wm2 + l * 32;
        for (int k = 0; k < 32; ++k) a = fmaf(h1[k], w[k], a);
        h2[l] = fmaxf(a, 0.f);
    }
    __syncthreads();
    if (l == 0) {
        float a = bm3[0];
        for (int k = 0; k < 16; ++k) a = fmaf(h2[k], Wm3[k], a);
        out[gi] = a;
    }
}

extern "C" void kernel_launch(void* const* d_in, const int* in_sizes, int n_in,
                              void* d_out, int out_size, void* d_ws, size_t ws_size,
                              hipStream_t stream) {
    const float* x      = (const float*)d_in[0];
    const int*   ei     = (const int*)  d_in[1];
    const int*   batch  = (const int*)  d_in[2];
    const float* ew     = (const float*)d_in[3];
    const float* W1r    = (const float*)d_in[4];
    const float* b1     = (const float*)d_in[5];
    const float* W1root = (const float*)d_in[6];
    const float* W2r    = (const float*)d_in[7];
    const float* b2     = (const float*)d_in[8];
    const float* W2root = (const float*)d_in[9];
    const float* W3r    = (const float*)d_in[10];
    const float* b3     = (const float*)d_in[11];
    const float* W3root = (const float*)d_in[12];
    const float* Wm1    = (const float*)d_in[13];
    const float* bm1    = (const float*)d_in[14];
    const float* Wm2    = (const float*)d_in[15];
    const float* bm2    = (const float*)d_in[16];
    const float* Wm3    = (const float*)d_in[17];
    const float* bm3    = (const float*)d_in[18];
    float* out = (float*)d_out;

    // ---- workspace layout ----
    float* agg1  = (float*)d_ws;                        // N*64 f32 (reused as agg3)
    float* agg2  = agg1 + (long)N_NODES * 64;           // N*128 f32 (reused: y3b + root3)
    float* POOL  = agg2 + (long)N_NODES * 128;          // 256*64
    int*   count    = (int*)(POOL + N_GRAPHS * 64);
    int*   offsets  = count + N_NODES;                  // N+1
    int*   cursor   = offsets + N_NODES + 1;            // N+1
    int*   gstart   = cursor + N_NODES + 1;             // 257
    int*   blocksum = gstart + N_GRAPHS + 1;            // SCAN_B
    int*   blockbase= blocksum + SCAN_B;                // SCAN_B
    uintptr_t wp = ((uintptr_t)(blockbase + SCAN_B) + 15) & ~(uintptr_t)15;
    unsigned long long* rec = (unsigned long long*)wp;  // E * 8B
    unsigned short* xb  = (unsigned short*)(rec + N_EDGES);  // N*64 bf16
    unsigned short* h1b = xb + (long)N_NODES * 64;           // N*128 bf16
    unsigned short* h2b = h1b + (long)N_NODES * 128;         // N*128 bf16
    unsigned short* Bh1 = h2b + (long)N_NODES * 128;         // 128*128
    unsigned short* Bl1 = Bh1 + 128 * 128;
    unsigned short* Bh2 = Bl1 + 128 * 128;                   // 128*256
    unsigned short* Bl2 = Bh2 + 128 * 256;
    unsigned short* Bh3 = Bl2 + 128 * 256;                   // 128*128
    unsigned short* Bl3 = Bh3 + 128 * 128;
    // layer-3 outputs carved from agg2 region (free after GEMM2):
    unsigned short* y3b = (unsigned short*)agg2;             // N*64 bf16
    float* root3 = agg2 + (long)N_NODES * 64;                // N*64 f32
    float* agg3  = agg1;                                     // N*64 f32

    const int gemm_grid = (N_NODES + 63) / 64;    // 782
    const int egrid = (N_EDGES + 255) / 256;

    // ---- weight pre-split + x->bf16 ----
    pack_w_kernel<<<(128 * 128 + 255) / 256, 256, 0, stream>>>(W1r, W1root, 64, 128, 0, Bh1, Bl1);
    pack_w_kernel<<<(128 * 256 + 255) / 256, 256, 0, stream>>>(W2r, W2root, 128, 256, 0, Bh2, Bl2);
    pack_w_kernel<<<(128 * 128 + 255) / 256, 256, 0, stream>>>(W3r, W3root, 128, 128, 1, Bh3, Bl3);
    cvt_bf16_kernel<<<(N_NODES * 64 / 4 + 255) / 256, 256, 0, stream>>>(x, xb, N_NODES * 64 / 4);

    // ---- CSR build ----
    hipMemsetAsync(count, 0, N_NODES * sizeof(int), stream);
    count_kernel<<<egrid, 256, 0, stream>>>(ei, count);
    scan_blocks_kernel<<<SCAN_B, 256, 0, stream>>>(count, blocksum);
    scan_base_kernel<<<1, 256, 0, stream>>>(blocksum, blockbase);
    scan_final_kernel<<<SCAN_B, 256, 0, stream>>>(count, blockbase, offsets, cursor);
    fill_kernel<<<2048, 256, 0, stream>>>(ei, ew, cursor, rec);
    gstart_kernel<<<1, 256, 0, stream>>>(batch, gstart);

    // ---- layer 1: agg1 = gather(xb); h1b = bf16(tanh([agg1|xb]@B1 + b1)) ----
    gather_agg<64><<<(N_NODES + 31) / 32, 256, 0, stream>>>(xb, 64, offsets, rec, agg1);
    gemm_mfma<64, 64, false, true><<<gemm_grid, 256, 0, stream>>>(
        agg1, 64, xb, 64, Bh1, Bl1, b1, h1b, nullptr);

    // ---- layer 2: agg2 = gather(h1b); h2b = bf16(tanh([agg2|h1b]@B2 + b2)) ----
    gather_agg<128><<<(N_NODES + 15) / 16, 256, 0, stream>>>(h1b, 128, offsets, rec, agg2);
    gemm_mfma<128, 128, false, true><<<gemm_grid, 256, 0, stream>>>(
        agg2, 128, h1b, 128, Bh2, Bl2, b2, h2b, nullptr);

    // ---- layer 3: y3b = bf16(h2b@W3r^T); root3 = h2b@W3root^T + b3 ----
    gemm_mfma<0, 128, true, false><<<gemm_grid, 256, 0, stream>>>(
        nullptr, 0, h2b, 128, Bh3, Bl3, b3, y3b, root3);
    gather_agg<64><<<(N_NODES + 31) / 32, 256, 0, stream>>>(y3b, 64, offsets, rec, agg3);

    // ---- pool + MLP ----
    pool_seg_kernel<<<N_GRAPHS, 256, 0, stream>>>(agg3, root3, gstart, POOL);
    mlp_kernel<<<N_GRAPHS, 64, 0, stream>>>(POOL, Wm1, bm1, Wm2, bm2, Wm3, bm3, out);
}

// Round 12
// 265.922 us; speedup vs baseline: 1.3033x; 1.1368x over previous
//
#include <hip/hip_runtime.h>

#define N_NODES 50000
#define N_EDGES 800000
#define N_GRAPHS 256
#define SCAN_B ((N_NODES + 255) / 256)
#define FILL_GROUPS 8
#define NPG (N_NODES / FILL_GROUPS)   // 6250 nodes per group

typedef __attribute__((ext_vector_type(8))) short bf16x8;
typedef __attribute__((ext_vector_type(4))) float f32x4;

__device__ inline unsigned short f2bf(float f) {
    unsigned int u = __float_as_uint(f);
    u += 0x7fff + ((u >> 16) & 1);          // RNE
    return (unsigned short)(u >> 16);
}
__device__ inline float bf2f(unsigned short h) {
    return __uint_as_float(((unsigned int)h) << 16);
}
__device__ inline float fast_tanh(float x) {
    return 1.0f - 2.0f / (__expf(2.0f * x) + 1.0f);
}

// ---------------------------------------------------------------------------
// weight pre-split: fp32 -> packed bf16 hi/lo, concatenated [128][KTOT]
// ---------------------------------------------------------------------------
__global__ void pack_w_kernel(const float* __restrict__ s0, const float* __restrict__ s1,
                              int K0, int KTOT, int nconcat,
                              unsigned short* __restrict__ hi, unsigned short* __restrict__ lo)
{
    const int idx = blockIdx.x * 256 + threadIdx.x;
    if (idx >= 128 * KTOT) return;
    const int c = idx / KTOT, k = idx % KTOT;
    float v;
    if (nconcat) v = (c < 64) ? s0[c * KTOT + k] : s1[(c - 64) * KTOT + k];
    else         v = (k < K0) ? s0[c * K0 + k]   : s1[c * K0 + (k - K0)];
    const unsigned short h = f2bf(v);
    hi[idx] = h;
    lo[idx] = f2bf(v - bf2f(h));
}

// ---------------------------------------------------------------------------
// fp32 -> bf16 convert (vectorized)
// ---------------------------------------------------------------------------
__global__ void cvt_bf16_kernel(const float* __restrict__ in,
                                unsigned short* __restrict__ out, int n4)
{
    const int i = blockIdx.x * 256 + threadIdx.x;
    if (i >= n4) return;
    const float4 v = ((const float4*)in)[i];
    ((ushort4*)out)[i] = make_ushort4(f2bf(v.x), f2bf(v.y), f2bf(v.z), f2bf(v.w));
}

// ---------------------------------------------------------------------------
// MFMA GEMM, mixed A chunks (fp32 on-the-fly split / exact bf16)
// ---------------------------------------------------------------------------
template<int KF32, int KB16, bool OUTSPLIT, bool ACT>
__global__ __launch_bounds__(256)
void gemm_mfma(const float* __restrict__ Af, int fstr,
               const unsigned short* __restrict__ Ab, int bstr,
               const unsigned short* __restrict__ Bhi, const unsigned short* __restrict__ Blo,
               const float* __restrict__ bias,
               unsigned short* __restrict__ C16, float* __restrict__ Cf)
{
    constexpr int KTOT = KF32 + KB16;
    constexpr int NCHF = KF32 / 32;
    constexpr int NCH  = KTOT / 32;

    __shared__ __align__(16) unsigned short lah[64 * 40];
    __shared__ __align__(16) unsigned short lal[64 * 40];
    __shared__ __align__(16) unsigned short lbh[128 * 40];
    __shared__ __align__(16) unsigned short lbl[128 * 40];

    const int tid = threadIdx.x;
    const int w = tid >> 6;
    const int lane = tid & 63;
    const int lrow = lane & 15;
    const int lkb = lane >> 4;
    const int m0 = blockIdx.x * 64;

    f32x4 acc[4][2] = {};

    for (int ch = 0; ch < NCH; ++ch) {
        const bool isF = (ch < NCHF);
        const int bk0 = ch * 32;

        __syncthreads();
        if (isF) {
            const int ak0 = ch * 32;
#pragma unroll
            for (int p = 0; p < 2; ++p) {
                const int f = tid + p * 256;
                const int r = f >> 3;
                const int q = f & 7;
                int row = m0 + r; if (row >= N_NODES) row = N_NODES - 1;
                const float4 v = *(const float4*)&Af[(long)row * fstr + ak0 + q * 4];
                const unsigned short h0 = f2bf(v.x), h1 = f2bf(v.y), h2 = f2bf(v.z), h3 = f2bf(v.w);
                *(ushort4*)&lah[r * 40 + q * 4] = make_ushort4(h0, h1, h2, h3);
                *(ushort4*)&lal[r * 40 + q * 4] =
                    make_ushort4(f2bf(v.x - bf2f(h0)), f2bf(v.y - bf2f(h1)),
                                 f2bf(v.z - bf2f(h2)), f2bf(v.w - bf2f(h3)));
            }
        } else {
            const int ak0 = (ch - NCHF) * 32;
            const int r = tid >> 2;
            const int q = tid & 3;
            int row = m0 + r; if (row >= N_NODES) row = N_NODES - 1;
            *(uint4*)&lah[r * 40 + q * 8] = *(const uint4*)&Ab[(long)row * bstr + ak0 + q * 8];
        }
#pragma unroll
        for (int p = 0; p < 2; ++p) {
            const int f = tid + p * 256;
            const int r = f >> 2;
            const int q = f & 3;
            const long g = (long)r * KTOT + bk0 + q * 8;
            *(uint4*)&lbh[r * 40 + q * 8] = *(const uint4*)&Bhi[g];
            *(uint4*)&lbl[r * 40 + q * 8] = *(const uint4*)&Blo[g];
        }
        __syncthreads();

        const int bo0 = (w * 32 + lrow) * 40 + lkb * 8;
        const int bo1 = bo0 + 16 * 40;
        const bf16x8 bh0 = *(const bf16x8*)&lbh[bo0];
        const bf16x8 bh1 = *(const bf16x8*)&lbh[bo1];
        const bf16x8 bl0 = *(const bf16x8*)&lbl[bo0];
        const bf16x8 bl1 = *(const bf16x8*)&lbl[bo1];
#pragma unroll
        for (int m = 0; m < 4; ++m) {
            const int ao = (m * 16 + lrow) * 40 + lkb * 8;
            const bf16x8 ah = *(const bf16x8*)&lah[ao];
            acc[m][0] = __builtin_amdgcn_mfma_f32_16x16x32_bf16(ah, bh0, acc[m][0], 0, 0, 0);
            acc[m][1] = __builtin_amdgcn_mfma_f32_16x16x32_bf16(ah, bh1, acc[m][1], 0, 0, 0);
            acc[m][0] = __builtin_amdgcn_mfma_f32_16x16x32_bf16(ah, bl0, acc[m][0], 0, 0, 0);
            acc[m][1] = __builtin_amdgcn_mfma_f32_16x16x32_bf16(ah, bl1, acc[m][1], 0, 0, 0);
            if (isF) {
                const bf16x8 al = *(const bf16x8*)&lal[ao];
                acc[m][0] = __builtin_amdgcn_mfma_f32_16x16x32_bf16(al, bh0, acc[m][0], 0, 0, 0);
                acc[m][1] = __builtin_amdgcn_mfma_f32_16x16x32_bf16(al, bh1, acc[m][1], 0, 0, 0);
            }
        }
    }

    const int c0 = w * 32 + lrow;
    if (!OUTSPLIT) {
        const float bb0 = bias[c0], bb1 = bias[c0 + 16];
#pragma unroll
        for (int m = 0; m < 4; ++m) {
#pragma unroll
            for (int r = 0; r < 4; ++r) {
                const int row = m0 + m * 16 + lkb * 4 + r;
                if (row < N_NODES) {
                    float v0 = acc[m][0][r] + bb0;
                    float v1 = acc[m][1][r] + bb1;
                    if (ACT) { v0 = fast_tanh(v0); v1 = fast_tanh(v1); }
                    C16[(long)row * 128 + c0]      = f2bf(v0);
                    C16[(long)row * 128 + c0 + 16] = f2bf(v1);
                }
            }
        }
    } else if (c0 < 64) {
#pragma unroll
        for (int m = 0; m < 4; ++m) {
#pragma unroll
            for (int r = 0; r < 4; ++r) {
                const int row = m0 + m * 16 + lkb * 4 + r;
                if (row < N_NODES) {
                    C16[(long)row * 64 + c0]      = f2bf(acc[m][0][r]);
                    C16[(long)row * 64 + c0 + 16] = f2bf(acc[m][1][r]);
                }
            }
        }
    } else {
        const float bb0 = bias[c0 - 64], bb1 = bias[c0 - 48];
#pragma unroll
        for (int m = 0; m < 4; ++m) {
#pragma unroll
            for (int r = 0; r < 4; ++r) {
                const int row = m0 + m * 16 + lkb * 4 + r;
                if (row < N_NODES) {
                    Cf[(long)row * 64 + c0 - 64] = acc[m][0][r] + bb0;
                    Cf[(long)row * 64 + c0 - 48] = acc[m][1][r] + bb1;
                }
            }
        }
    }
}

// ---------------------------------------------------------------------------
// CSR build: count -> hierarchical scan -> XCD-localized fill
// ---------------------------------------------------------------------------
__global__ void count_kernel(const int* __restrict__ ei, int* __restrict__ count)
{
    const int e = blockIdx.x * blockDim.x + threadIdx.x;
    if (e < N_EDGES) atomicAdd(&count[ei[N_EDGES + e]], 1);
}

__global__ __launch_bounds__(256)
void scan_blocks_kernel(const int* __restrict__ count, int* __restrict__ blocksum)
{
    __shared__ int red[256];
    const int i = blockIdx.x * 256 + threadIdx.x;
    red[threadIdx.x] = (i < N_NODES) ? count[i] : 0;
    __syncthreads();
#pragma unroll
    for (int d = 128; d > 0; d >>= 1) {
        if (threadIdx.x < d) red[threadIdx.x] += red[threadIdx.x + d];
        __syncthreads();
    }
    if (threadIdx.x == 0) blocksum[blockIdx.x] = red[0];
}

__global__ __launch_bounds__(256)
void scan_base_kernel(const int* __restrict__ blocksum, int* __restrict__ blockbase)
{
    __shared__ int s[256];
    const int t = threadIdx.x;
    const int own = (t < SCAN_B) ? blocksum[t] : 0;
    s[t] = own;
    __syncthreads();
#pragma unroll
    for (int d = 1; d < 256; d <<= 1) {
        const int v = (t >= d) ? s[t - d] : 0;
        __syncthreads();
        s[t] += v;
        __syncthreads();
    }
    if (t < SCAN_B) blockbase[t] = s[t] - own;
}

__global__ __launch_bounds__(256)
void scan_final_kernel(const int* __restrict__ count, const int* __restrict__ blockbase,
                       int* __restrict__ offsets, int* __restrict__ cursor)
{
    __shared__ int s[256];
    const int t = threadIdx.x;
    const int i = blockIdx.x * 256 + t;
    const int v = (i < N_NODES) ? count[i] : 0;
    s[t] = v;
    __syncthreads();
#pragma unroll
    for (int d = 1; d < 256; d <<= 1) {
        const int u = (t >= d) ? s[t - d] : 0;
        __syncthreads();
        s[t] += u;
        __syncthreads();
    }
    if (i < N_NODES) {
        const int off = blockbase[blockIdx.x] + s[t] - v;
        offsets[i] = off;
        cursor[i] = off;
    }
    if (i == 0) offsets[N_NODES] = N_EDGES;
}

// XCD-localized fill; int4-vectorized dst scan (4 edges/thread/iter)
__global__ __launch_bounds__(256)
void fill_kernel(const int* __restrict__ ei, const float* __restrict__ ew,
                 int* __restrict__ cursor, uint2* __restrict__ rec)
{
    const int g = blockIdx.x & (FILL_GROUPS - 1);
    const int q = blockIdx.x >> 3;
    const int nlo = g * NPG;
    const int nhi = nlo + NPG;
    const int stride = (gridDim.x >> 3) * 256;
    const int4* dst4 = (const int4*)(ei + N_EDGES);
    for (int e4 = q * 256 + threadIdx.x; e4 < N_EDGES / 4; e4 += stride) {
        const int4 t4 = dst4[e4];
#pragma unroll
        for (int k = 0; k < 4; ++k) {
            const int t = (&t4.x)[k];
            if (t >= nlo && t < nhi) {
                const int e = e4 * 4 + k;
                const int pos = atomicAdd(&cursor[t], 1);
                rec[pos] = make_uint2((unsigned)ei[e], __float_as_uint(ew[e]));
            }
        }
    }
}

// ---------------------------------------------------------------------------
// gather aggregation over bf16 features, fp32 accumulate. D/8 lanes per node.
// FUSE: h3 = tanh(agg + root) written directly (layer 3).
// ---------------------------------------------------------------------------
template<int D, bool FUSE>
__global__ __launch_bounds__(256)
void gather_agg(const unsigned short* __restrict__ feat, int stride,
                const int* __restrict__ offsets, const uint2* __restrict__ rec,
                const float* __restrict__ root, float* __restrict__ agg)
{
    constexpr int LPN = D / 8;
    constexpr int NPB = 256 / LPN;
    const int lane = threadIdx.x % LPN;
    const int slot = threadIdx.x / LPN;
    const int n = blockIdx.x * NPB + slot;
    if (n >= N_NODES) return;
    const int lo = offsets[n], hi = offsets[n + 1];
    const int j = lane * 8;
    float a0[8] = {}, a1[8] = {};
    int e = lo;
    for (; e + 1 < hi; e += 2) {
        const uint2 r0 = rec[e];
        const uint2 r1 = rec[e + 1];
        const bf16x8 v0 = *(const bf16x8*)&feat[(long)r0.x * stride + j];
        const bf16x8 v1 = *(const bf16x8*)&feat[(long)r1.x * stride + j];
        const float w0 = __uint_as_float(r0.y);
        const float w1 = __uint_as_float(r1.y);
#pragma unroll
        for (int k = 0; k < 8; ++k) {
            a0[k] = fmaf(bf2f((unsigned short)v0[k]), w0, a0[k]);
            a1[k] = fmaf(bf2f((unsigned short)v1[k]), w1, a1[k]);
        }
    }
    if (e < hi) {
        const uint2 r = rec[e];
        const bf16x8 v = *(const bf16x8*)&feat[(long)r.x * stride + j];
        const float w = __uint_as_float(r.y);
#pragma unroll
        for (int k = 0; k < 8; ++k)
            a0[k] = fmaf(bf2f((unsigned short)v[k]), w, a0[k]);
    }
    float o[8];
#pragma unroll
    for (int k = 0; k < 8; ++k) o[k] = a0[k] + a1[k];
    if (FUSE) {
        const float4 rt0 = *(const float4*)&root[(long)n * D + j];
        const float4 rt1 = *(const float4*)&root[(long)n * D + j + 4];
        o[0] = fast_tanh(o[0] + rt0.x); o[1] = fast_tanh(o[1] + rt0.y);
        o[2] = fast_tanh(o[2] + rt0.z); o[3] = fast_tanh(o[3] + rt0.w);
        o[4] = fast_tanh(o[4] + rt1.x); o[5] = fast_tanh(o[5] + rt1.y);
        o[6] = fast_tanh(o[6] + rt1.z); o[7] = fast_tanh(o[7] + rt1.w);
    }
    *(float4*)&agg[(long)n * D + j]     = make_float4(o[0], o[1], o[2], o[3]);
    *(float4*)&agg[(long)n * D + j + 4] = make_float4(o[4], o[5], o[6], o[7]);
}

// ---------------------------------------------------------------------------
// pool (sum of h3 per graph) + MLP
// ---------------------------------------------------------------------------
__global__ void gstart_kernel(const int* __restrict__ batch, int* __restrict__ gstart)
{
    const int g = threadIdx.x;
    int lo = 0, hi = N_NODES;
    while (lo < hi) { const int mid = (lo + hi) >> 1; if (batch[mid] < g) lo = mid + 1; else hi = mid; }
    gstart[g] = lo;
    if (g == 0) gstart[N_GRAPHS] = N_NODES;
}

__global__ __launch_bounds__(256)
void pool_seg_kernel(const float* __restrict__ h3,
                     const int* __restrict__ gstart, float* __restrict__ g)
{
    const int gi = blockIdx.x;
    const int c = threadIdx.x & 63;
    const int sub = threadIdx.x >> 6;
    const int lo = gstart[gi], hi = gstart[gi + 1];
    float acc = 0.f;
    for (int n = lo + sub; n < hi; n += 4)
        acc += h3[(long)n * 64 + c];
    __shared__ float red[256];
    red[threadIdx.x] = acc;
    __syncthreads();
    if (sub == 0) g[gi * 64 + c] = red[c] + red[64 + c] + red[128 + c] + red[192 + c];
}

__global__ __launch_bounds__(64)
void mlp_kernel(const float* __restrict__ g,
                const float* __restrict__ Wm1, const float* __restrict__ bm1,
                const float* __restrict__ Wm2, const float* __restrict__ bm2,
                const float* __restrict__ Wm3, const float* __restrict__ bm3,
                float* __restrict__ out)
{
    const int gi = blockIdx.x;
    const int l = threadIdx.x;
    __shared__ float gr[64], h1[32], h2[16];
    gr[l] = g[gi * 64 + l];
    __syncthreads();
    if (l < 32) {
        float a = bm1[l];
        const float* w = Wm1 + l * 64;
        for (int k = 0; k < 64; ++k) a = fmaf(gr[k], w[k], a);
        h1[l] = fmaxf(a, 0.f);
    }
    __syncthreads();
    if (l < 16) {
        float a = bm2[l];
        const float* w = Wm2 + l * 32;
        for (int k = 0; k < 32; ++k) a = fmaf(h1[k], w[k], a);
        h2[l] = fmaxf(a, 0.f);
    }
    __syncthreads();
    if (l == 0) {
        float a = bm3[0];
        for (int k = 0; k < 16; ++k) a = fmaf(h2[k], Wm3[k], a);
        out[gi] = a;
    }
}

extern "C" void kernel_launch(void* const* d_in, const int* in_sizes, int n_in,
                              void* d_out, int out_size, void* d_ws, size_t ws_size,
                              hipStream_t stream) {
    const float* x      = (const float*)d_in[0];
    const int*   ei     = (const int*)  d_in[1];
    const int*   batch  = (const int*)  d_in[2];
    const float* ew     = (const float*)d_in[3];
    const float* W1r    = (const float*)d_in[4];
    const float* b1     = (const float*)d_in[5];
    const float* W1root = (const float*)d_in[6];
    const float* W2r    = (const float*)d_in[7];
    const float* b2     = (const float*)d_in[8];
    const float* W2root = (const float*)d_in[9];
    const float* W3r    = (const float*)d_in[10];
    const float* b3     = (const float*)d_in[11];
    const float* W3root = (const float*)d_in[12];
    const float* Wm1    = (const float*)d_in[13];
    const float* bm1    = (const float*)d_in[14];
    const float* Wm2    = (const float*)d_in[15];
    const float* bm2    = (const float*)d_in[16];
    const float* Wm3    = (const float*)d_in[17];
    const float* bm3    = (const float*)d_in[18];
    float* out = (float*)d_out;

    // ---- workspace layout ----
    float* agg1  = (float*)d_ws;                        // N*64 f32 (reused as h3)
    float* agg2  = agg1 + (long)N_NODES * 64;           // N*128 f32 (reused: y3b + root3)
    float* POOL  = agg2 + (long)N_NODES * 128;          // 256*64
    int*   count    = (int*)(POOL + N_GRAPHS * 64);
    int*   offsets  = count + N_NODES;                  // N+1
    int*   cursor   = offsets + N_NODES + 1;            // N+1
    int*   gstart   = cursor + N_NODES + 1;             // 257
    int*   blocksum = gstart + N_GRAPHS + 1;            // SCAN_B
    int*   blockbase= blocksum + SCAN_B;                // SCAN_B
    uintptr_t wp = ((uintptr_t)(blockbase + SCAN_B) + 15) & ~(uintptr_t)15;
    uint2* rec = (uint2*)wp;                            // E * 8B
    unsigned short* xb  = (unsigned short*)(rec + N_EDGES);  // N*64 bf16
    unsigned short* h1b = xb + (long)N_NODES * 64;           // N*128 bf16
    unsigned short* h2b = h1b + (long)N_NODES * 128;         // N*128 bf16
    unsigned short* Bh1 = h2b + (long)N_NODES * 128;         // 128*128
    unsigned short* Bl1 = Bh1 + 128 * 128;
    unsigned short* Bh2 = Bl1 + 128 * 128;                   // 128*256
    unsigned short* Bl2 = Bh2 + 128 * 256;
    unsigned short* Bh3 = Bl2 + 128 * 256;                   // 128*128
    unsigned short* Bl3 = Bh3 + 128 * 128;
    // layer-3 outputs carved from agg2 region (free after GEMM2):
    unsigned short* y3b = (unsigned short*)agg2;             // N*64 bf16
    float* root3 = agg2 + (long)N_NODES * 64;                // N*64 f32
    float* h3    = agg1;                                     // N*64 f32

    const int gemm_grid = (N_NODES + 63) / 64;    // 782
    const int egrid = (N_EDGES + 255) / 256;

    // ---- weight pre-split + x->bf16 ----
    pack_w_kernel<<<(128 * 128 + 255) / 256, 256, 0, stream>>>(W1r, W1root, 64, 128, 0, Bh1, Bl1);
    pack_w_kernel<<<(128 * 256 + 255) / 256, 256, 0, stream>>>(W2r, W2root, 128, 256, 0, Bh2, Bl2);
    pack_w_kernel<<<(128 * 128 + 255) / 256, 256, 0, stream>>>(W3r, W3root, 128, 128, 1, Bh3, Bl3);
    cvt_bf16_kernel<<<(N_NODES * 64 / 4 + 255) / 256, 256, 0, stream>>>(x, xb, N_NODES * 64 / 4);

    // ---- CSR build ----
    hipMemsetAsync(count, 0, N_NODES * sizeof(int), stream);
    count_kernel<<<egrid, 256, 0, stream>>>(ei, count);
    scan_blocks_kernel<<<SCAN_B, 256, 0, stream>>>(count, blocksum);
    scan_base_kernel<<<1, 256, 0, stream>>>(blocksum, blockbase);
    scan_final_kernel<<<SCAN_B, 256, 0, stream>>>(count, blockbase, offsets, cursor);
    fill_kernel<<<2048, 256, 0, stream>>>(ei, ew, cursor, rec);
    gstart_kernel<<<1, 256, 0, stream>>>(batch, gstart);

    // ---- layer 1: agg1 = gather(xb); h1b = bf16(tanh([agg1|xb]@B1 + b1)) ----
    gather_agg<64, false><<<(N_NODES + 31) / 32, 256, 0, stream>>>(xb, 64, offsets, rec, nullptr, agg1);
    gemm_mfma<64, 64, false, true><<<gemm_grid, 256, 0, stream>>>(
        agg1, 64, xb, 64, Bh1, Bl1, b1, h1b, nullptr);

    // ---- layer 2: agg2 = gather(h1b); h2b = bf16(tanh([agg2|h1b]@B2 + b2)) ----
    gather_agg<128, false><<<(N_NODES + 15) / 16, 256, 0, stream>>>(h1b, 128, offsets, rec, nullptr, agg2);
    gemm_mfma<128, 128, false, true><<<gemm_grid, 256, 0, stream>>>(
        agg2, 128, h1b, 128, Bh2, Bl2, b2, h2b, nullptr);

    // ---- layer 3: y3b = bf16(h2b@W3r^T); root3 = h2b@W3root^T + b3 ----
    gemm_mfma<0, 128, true, false><<<gemm_grid, 256, 0, stream>>>(
        nullptr, 0, h2b, 128, Bh3, Bl3, b3, y3b, root3);
    // fused: h3 = tanh(gather(y3b) + root3)
    gather_agg<64, true><<<(N_NODES + 31) / 32, 256, 0, stream>>>(y3b, 64, offsets, rec, root3, h3);

    // ---- pool + MLP ----
    pool_seg_kernel<<<N_GRAPHS, 256, 0, stream>>>(h3, gstart, POOL);
    mlp_kernel<<<N_GRAPHS, 64, 0, stream>>>(POOL, Wm1, bm1, Wm2, bm2, Wm3, bm3, out);
}

// Round 13
// 254.105 us; speedup vs baseline: 1.3639x; 1.0465x over previous
//
#include <hip/hip_runtime.h>

#define N_NODES 50000
#define N_EDGES 800000
#define N_GRAPHS 256
#define SCAN_B ((N_NODES + 255) / 256)
#define FILL_GROUPS 8
#define NPG (N_NODES / FILL_GROUPS)   // 6250 nodes per group

typedef __attribute__((ext_vector_type(8))) short bf16x8;
typedef __attribute__((ext_vector_type(4))) float f32x4;

__device__ inline unsigned short f2bf(float f) {
    unsigned int u = __float_as_uint(f);
    u += 0x7fff + ((u >> 16) & 1);          // RNE
    return (unsigned short)(u >> 16);
}
__device__ inline float bf2f(unsigned short h) {
    return __uint_as_float(((unsigned int)h) << 16);
}
__device__ inline float fast_tanh(float x) {
    return 1.0f - 2.0f / (__expf(2.0f * x) + 1.0f);
}

// ---------------------------------------------------------------------------
// fused prep: 3x weight pre-split + x->bf16 + edge count  (independent work)
// block ranges: [0,64) pack1, [64,192) pack2, [192,256) pack3,
//               [256,3381) cvt, [3381,6506) count
// ---------------------------------------------------------------------------
__device__ inline void pack_w_body(int idx, const float* __restrict__ s0,
                                   const float* __restrict__ s1, int K0, int KTOT,
                                   int nconcat, unsigned short* __restrict__ hi,
                                   unsigned short* __restrict__ lo)
{
    const int c = idx / KTOT, k = idx % KTOT;
    float v;
    if (nconcat) v = (c < 64) ? s0[c * KTOT + k] : s1[(c - 64) * KTOT + k];
    else         v = (k < K0) ? s0[c * K0 + k]   : s1[c * K0 + (k - K0)];
    const unsigned short h = f2bf(v);
    hi[idx] = h;
    lo[idx] = f2bf(v - bf2f(h));
}

__global__ __launch_bounds__(256)
void prep_kernel(const float* __restrict__ W1r, const float* __restrict__ W1root,
                 const float* __restrict__ W2r, const float* __restrict__ W2root,
                 const float* __restrict__ W3r, const float* __restrict__ W3root,
                 unsigned short* __restrict__ Bh1, unsigned short* __restrict__ Bl1,
                 unsigned short* __restrict__ Bh2, unsigned short* __restrict__ Bl2,
                 unsigned short* __restrict__ Bh3, unsigned short* __restrict__ Bl3,
                 const float* __restrict__ x, unsigned short* __restrict__ xb,
                 const int* __restrict__ ei, int* __restrict__ count)
{
    const int b = blockIdx.x;
    const int t = threadIdx.x;
    if (b < 64) {
        pack_w_body(b * 256 + t, W1r, W1root, 64, 128, 0, Bh1, Bl1);
    } else if (b < 192) {
        pack_w_body((b - 64) * 256 + t, W2r, W2root, 128, 256, 0, Bh2, Bl2);
    } else if (b < 256) {
        pack_w_body((b - 192) * 256 + t, W3r, W3root, 128, 128, 1, Bh3, Bl3);
    } else if (b < 3381) {
        const int i = (b - 256) * 256 + t;
        if (i < N_NODES * 64 / 4) {
            const float4 v = ((const float4*)x)[i];
            ((ushort4*)xb)[i] = make_ushort4(f2bf(v.x), f2bf(v.y), f2bf(v.z), f2bf(v.w));
        }
    } else {
        const int e = (b - 3381) * 256 + t;
        if (e < N_EDGES) atomicAdd(&count[ei[N_EDGES + e]], 1);
    }
}

// ---------------------------------------------------------------------------
// MFMA GEMM, mixed A chunks (fp32 on-the-fly split / exact bf16)
// ---------------------------------------------------------------------------
template<int KF32, int KB16, bool OUTSPLIT, bool ACT>
__global__ __launch_bounds__(256)
void gemm_mfma(const float* __restrict__ Af, int fstr,
               const unsigned short* __restrict__ Ab, int bstr,
               const unsigned short* __restrict__ Bhi, const unsigned short* __restrict__ Blo,
               const float* __restrict__ bias,
               unsigned short* __restrict__ C16, float* __restrict__ Cf)
{
    constexpr int KTOT = KF32 + KB16;
    constexpr int NCHF = KF32 / 32;
    constexpr int NCH  = KTOT / 32;

    __shared__ __align__(16) unsigned short lah[64 * 40];
    __shared__ __align__(16) unsigned short lal[64 * 40];
    __shared__ __align__(16) unsigned short lbh[128 * 40];
    __shared__ __align__(16) unsigned short lbl[128 * 40];

    const int tid = threadIdx.x;
    const int w = tid >> 6;
    const int lane = tid & 63;
    const int lrow = lane & 15;
    const int lkb = lane >> 4;
    const int m0 = blockIdx.x * 64;

    f32x4 acc[4][2] = {};

    for (int ch = 0; ch < NCH; ++ch) {
        const bool isF = (ch < NCHF);
        const int bk0 = ch * 32;

        __syncthreads();
        if (isF) {
            const int ak0 = ch * 32;
#pragma unroll
            for (int p = 0; p < 2; ++p) {
                const int f = tid + p * 256;
                const int r = f >> 3;
                const int q = f & 7;
                int row = m0 + r; if (row >= N_NODES) row = N_NODES - 1;
                const float4 v = *(const float4*)&Af[(long)row * fstr + ak0 + q * 4];
                const unsigned short h0 = f2bf(v.x), h1 = f2bf(v.y), h2 = f2bf(v.z), h3 = f2bf(v.w);
                *(ushort4*)&lah[r * 40 + q * 4] = make_ushort4(h0, h1, h2, h3);
                *(ushort4*)&lal[r * 40 + q * 4] =
                    make_ushort4(f2bf(v.x - bf2f(h0)), f2bf(v.y - bf2f(h1)),
                                 f2bf(v.z - bf2f(h2)), f2bf(v.w - bf2f(h3)));
            }
        } else {
            const int ak0 = (ch - NCHF) * 32;
            const int r = tid >> 2;
            const int q = tid & 3;
            int row = m0 + r; if (row >= N_NODES) row = N_NODES - 1;
            *(uint4*)&lah[r * 40 + q * 8] = *(const uint4*)&Ab[(long)row * bstr + ak0 + q * 8];
        }
#pragma unroll
        for (int p = 0; p < 2; ++p) {
            const int f = tid + p * 256;
            const int r = f >> 2;
            const int q = f & 3;
            const long g = (long)r * KTOT + bk0 + q * 8;
            *(uint4*)&lbh[r * 40 + q * 8] = *(const uint4*)&Bhi[g];
            *(uint4*)&lbl[r * 40 + q * 8] = *(const uint4*)&Blo[g];
        }
        __syncthreads();

        const int bo0 = (w * 32 + lrow) * 40 + lkb * 8;
        const int bo1 = bo0 + 16 * 40;
        const bf16x8 bh0 = *(const bf16x8*)&lbh[bo0];
        const bf16x8 bh1 = *(const bf16x8*)&lbh[bo1];
        const bf16x8 bl0 = *(const bf16x8*)&lbl[bo0];
        const bf16x8 bl1 = *(const bf16x8*)&lbl[bo1];
#pragma unroll
        for (int m = 0; m < 4; ++m) {
            const int ao = (m * 16 + lrow) * 40 + lkb * 8;
            const bf16x8 ah = *(const bf16x8*)&lah[ao];
            acc[m][0] = __builtin_amdgcn_mfma_f32_16x16x32_bf16(ah, bh0, acc[m][0], 0, 0, 0);
            acc[m][1] = __builtin_amdgcn_mfma_f32_16x16x32_bf16(ah, bh1, acc[m][1], 0, 0, 0);
            acc[m][0] = __builtin_amdgcn_mfma_f32_16x16x32_bf16(ah, bl0, acc[m][0], 0, 0, 0);
            acc[m][1] = __builtin_amdgcn_mfma_f32_16x16x32_bf16(ah, bl1, acc[m][1], 0, 0, 0);
            if (isF) {
                const bf16x8 al = *(const bf16x8*)&lal[ao];
                acc[m][0] = __builtin_amdgcn_mfma_f32_16x16x32_bf16(al, bh0, acc[m][0], 0, 0, 0);
                acc[m][1] = __builtin_amdgcn_mfma_f32_16x16x32_bf16(al, bh1, acc[m][1], 0, 0, 0);
            }
        }
    }

    const int c0 = w * 32 + lrow;
    if (!OUTSPLIT) {
        const float bb0 = bias[c0], bb1 = bias[c0 + 16];
#pragma unroll
        for (int m = 0; m < 4; ++m) {
#pragma unroll
            for (int r = 0; r < 4; ++r) {
                const int row = m0 + m * 16 + lkb * 4 + r;
                if (row < N_NODES) {
                    float v0 = acc[m][0][r] + bb0;
                    float v1 = acc[m][1][r] + bb1;
                    if (ACT) { v0 = fast_tanh(v0); v1 = fast_tanh(v1); }
                    C16[(long)row * 128 + c0]      = f2bf(v0);
                    C16[(long)row * 128 + c0 + 16] = f2bf(v1);
                }
            }
        }
    } else if (c0 < 64) {
#pragma unroll
        for (int m = 0; m < 4; ++m) {
#pragma unroll
            for (int r = 0; r < 4; ++r) {
                const int row = m0 + m * 16 + lkb * 4 + r;
                if (row < N_NODES) {
                    C16[(long)row * 64 + c0]      = f2bf(acc[m][0][r]);
                    C16[(long)row * 64 + c0 + 16] = f2bf(acc[m][1][r]);
                }
            }
        }
    } else {
        const float bb0 = bias[c0 - 64], bb1 = bias[c0 - 48];
#pragma unroll
        for (int m = 0; m < 4; ++m) {
#pragma unroll
            for (int r = 0; r < 4; ++r) {
                const int row = m0 + m * 16 + lkb * 4 + r;
                if (row < N_NODES) {
                    Cf[(long)row * 64 + c0 - 64] = acc[m][0][r] + bb0;
                    Cf[(long)row * 64 + c0 - 48] = acc[m][1][r] + bb1;
                }
            }
        }
    }
}

// ---------------------------------------------------------------------------
// hierarchical scan (+ gstart fused into last kernel)
// ---------------------------------------------------------------------------
__global__ __launch_bounds__(256)
void scan_blocks_kernel(const int* __restrict__ count, int* __restrict__ blocksum)
{
    __shared__ int red[256];
    const int i = blockIdx.x * 256 + threadIdx.x;
    red[threadIdx.x] = (i < N_NODES) ? count[i] : 0;
    __syncthreads();
#pragma unroll
    for (int d = 128; d > 0; d >>= 1) {
        if (threadIdx.x < d) red[threadIdx.x] += red[threadIdx.x + d];
        __syncthreads();
    }
    if (threadIdx.x == 0) blocksum[blockIdx.x] = red[0];
}

__global__ __launch_bounds__(256)
void scan_base_kernel(const int* __restrict__ blocksum, int* __restrict__ blockbase)
{
    __shared__ int s[256];
    const int t = threadIdx.x;
    const int own = (t < SCAN_B) ? blocksum[t] : 0;
    s[t] = own;
    __syncthreads();
#pragma unroll
    for (int d = 1; d < 256; d <<= 1) {
        const int v = (t >= d) ? s[t - d] : 0;
        __syncthreads();
        s[t] += v;
        __syncthreads();
    }
    if (t < SCAN_B) blockbase[t] = s[t] - own;
}

__global__ __launch_bounds__(256)
void scan_final_kernel(const int* __restrict__ count, const int* __restrict__ blockbase,
                       int* __restrict__ offsets, int* __restrict__ cursor,
                       const int* __restrict__ batch, int* __restrict__ gstart)
{
    if (blockIdx.x == SCAN_B) {      // fused gstart (batch is sorted)
        const int g = threadIdx.x;
        int lo = 0, hi = N_NODES;
        while (lo < hi) { const int mid = (lo + hi) >> 1; if (batch[mid] < g) lo = mid + 1; else hi = mid; }
        gstart[g] = lo;
        if (g == 0) gstart[N_GRAPHS] = N_NODES;
        return;
    }
    __shared__ int s[256];
    const int t = threadIdx.x;
    const int i = blockIdx.x * 256 + t;
    const int v = (i < N_NODES) ? count[i] : 0;
    s[t] = v;
    __syncthreads();
#pragma unroll
    for (int d = 1; d < 256; d <<= 1) {
        const int u = (t >= d) ? s[t - d] : 0;
        __syncthreads();
        s[t] += u;
        __syncthreads();
    }
    if (i < N_NODES) {
        const int off = blockbase[blockIdx.x] + s[t] - v;
        offsets[i] = off;
        cursor[i] = off;
    }
    if (i == 0) offsets[N_NODES] = N_EDGES;
}

// XCD-localized fill; int4-vectorized dst scan (4 edges/thread/iter)
__global__ __launch_bounds__(256)
void fill_kernel(const int* __restrict__ ei, const float* __restrict__ ew,
                 int* __restrict__ cursor, uint2* __restrict__ rec)
{
    const int g = blockIdx.x & (FILL_GROUPS - 1);
    const int q = blockIdx.x >> 3;
    const int nlo = g * NPG;
    const int nhi = nlo + NPG;
    const int stride = (gridDim.x >> 3) * 256;
    const int4* dst4 = (const int4*)(ei + N_EDGES);
    for (int e4 = q * 256 + threadIdx.x; e4 < N_EDGES / 4; e4 += stride) {
        const int4 t4 = dst4[e4];
#pragma unroll
        for (int k = 0; k < 4; ++k) {
            const int t = (&t4.x)[k];
            if (t >= nlo && t < nhi) {
                const int e = e4 * 4 + k;
                const int pos = atomicAdd(&cursor[t], 1);
                rec[pos] = make_uint2((unsigned)ei[e], __float_as_uint(ew[e]));
            }
        }
    }
}

// ---------------------------------------------------------------------------
// gather aggregation over bf16 features, fp32 accumulate. D/8 lanes per node.
// FUSE: h3 = tanh(agg + root) written directly (layer 3).
// ---------------------------------------------------------------------------
template<int D, bool FUSE>
__global__ __launch_bounds__(256)
void gather_agg(const unsigned short* __restrict__ feat, int stride,
                const int* __restrict__ offsets, const uint2* __restrict__ rec,
                const float* __restrict__ root, float* __restrict__ agg)
{
    constexpr int LPN = D / 8;
    constexpr int NPB = 256 / LPN;
    const int lane = threadIdx.x % LPN;
    const int slot = threadIdx.x / LPN;
    const int n = blockIdx.x * NPB + slot;
    if (n >= N_NODES) return;
    const int lo = offsets[n], hi = offsets[n + 1];
    const int j = lane * 8;
    float a0[8] = {}, a1[8] = {};
    int e = lo;
    for (; e + 1 < hi; e += 2) {
        const uint2 r0 = rec[e];
        const uint2 r1 = rec[e + 1];
        const bf16x8 v0 = *(const bf16x8*)&feat[(long)r0.x * stride + j];
        const bf16x8 v1 = *(const bf16x8*)&feat[(long)r1.x * stride + j];
        const float w0 = __uint_as_float(r0.y);
        const float w1 = __uint_as_float(r1.y);
#pragma unroll
        for (int k = 0; k < 8; ++k) {
            a0[k] = fmaf(bf2f((unsigned short)v0[k]), w0, a0[k]);
            a1[k] = fmaf(bf2f((unsigned short)v1[k]), w1, a1[k]);
        }
    }
    if (e < hi) {
        const uint2 r = rec[e];
        const bf16x8 v = *(const bf16x8*)&feat[(long)r.x * stride + j];
        const float w = __uint_as_float(r.y);
#pragma unroll
        for (int k = 0; k < 8; ++k)
            a0[k] = fmaf(bf2f((unsigned short)v[k]), w, a0[k]);
    }
    float o[8];
#pragma unroll
    for (int k = 0; k < 8; ++k) o[k] = a0[k] + a1[k];
    if (FUSE) {
        const float4 rt0 = *(const float4*)&root[(long)n * D + j];
        const float4 rt1 = *(const float4*)&root[(long)n * D + j + 4];
        o[0] = fast_tanh(o[0] + rt0.x); o[1] = fast_tanh(o[1] + rt0.y);
        o[2] = fast_tanh(o[2] + rt0.z); o[3] = fast_tanh(o[3] + rt0.w);
        o[4] = fast_tanh(o[4] + rt1.x); o[5] = fast_tanh(o[5] + rt1.y);
        o[6] = fast_tanh(o[6] + rt1.z); o[7] = fast_tanh(o[7] + rt1.w);
    }
    *(float4*)&agg[(long)n * D + j]     = make_float4(o[0], o[1], o[2], o[3]);
    *(float4*)&agg[(long)n * D + j + 4] = make_float4(o[4], o[5], o[6], o[7]);
}

// ---------------------------------------------------------------------------
// fused pool + MLP: block gi reduces graph gi's nodes, then runs 64->32->16->1
// ---------------------------------------------------------------------------
__global__ __launch_bounds__(256)
void pool_mlp_kernel(const float* __restrict__ h3, const int* __restrict__ gstart,
                     const float* __restrict__ Wm1, const float* __restrict__ bm1,
                     const float* __restrict__ Wm2, const float* __restrict__ bm2,
                     const float* __restrict__ Wm3, const float* __restrict__ bm3,
                     float* __restrict__ out)
{
    const int gi = blockIdx.x;
    const int tid = threadIdx.x;
    const int c = tid & 63;
    const int sub = tid >> 6;
    const int lo = gstart[gi], hi = gstart[gi + 1];
    float acc = 0.f;
    for (int n = lo + sub; n < hi; n += 4)
        acc += h3[(long)n * 64 + c];
    __shared__ float red[256];
    __shared__ float gr[64], h1[32], h2[16];
    red[tid] = acc;
    __syncthreads();
    if (sub == 0) gr[c] = red[c] + red[64 + c] + red[128 + c] + red[192 + c];
    __syncthreads();
    if (tid < 32) {
        float a = bm1[tid];
        const float* w = Wm1 + tid * 64;
#pragma unroll 8
        for (int k = 0; k < 64; ++k) a = fmaf(gr[k], w[k], a);
        h1[tid] = fmaxf(a, 0.f);
    }
    __syncthreads();
    if (tid < 16) {
        float a = bm2[tid];
        const float* w = Wm2 + tid * 32;
#pragma unroll 8
        for (int k = 0; k < 32; ++k) a = fmaf(h1[k], w[k], a);
        h2[tid] = fmaxf(a, 0.f);
    }
    __syncthreads();
    if (tid == 0) {
        float a = bm3[0];
#pragma unroll
        for (int k = 0; k < 16; ++k) a = fmaf(h2[k], Wm3[k], a);
        out[gi] = a;
    }
}

extern "C" void kernel_launch(void* const* d_in, const int* in_sizes, int n_in,
                              void* d_out, int out_size, void* d_ws, size_t ws_size,
                              hipStream_t stream) {
    const float* x      = (const float*)d_in[0];
    const int*   ei     = (const int*)  d_in[1];
    const int*   batch  = (const int*)  d_in[2];
    const float* ew     = (const float*)d_in[3];
    const float* W1r    = (const float*)d_in[4];
    const float* b1     = (const float*)d_in[5];
    const float* W1root = (const float*)d_in[6];
    const float* W2r    = (const float*)d_in[7];
    const float* b2     = (const float*)d_in[8];
    const float* W2root = (const float*)d_in[9];
    const float* W3r    = (const float*)d_in[10];
    const float* b3     = (const float*)d_in[11];
    const float* W3root = (const float*)d_in[12];
    const float* Wm1    = (const float*)d_in[13];
    const float* bm1    = (const float*)d_in[14];
    const float* Wm2    = (const float*)d_in[15];
    const float* bm2    = (const float*)d_in[16];
    const float* Wm3    = (const float*)d_in[17];
    const float* bm3    = (const float*)d_in[18];
    float* out = (float*)d_out;

    // ---- workspace layout ----
    float* agg1  = (float*)d_ws;                        // N*64 f32 (reused as h3)
    float* agg2  = agg1 + (long)N_NODES * 64;           // N*128 f32 (reused: y3b + root3)
    float* POOL  = agg2 + (long)N_NODES * 128;          // 256*64 (unused now)
    int*   count    = (int*)(POOL + N_GRAPHS * 64);
    int*   offsets  = count + N_NODES;                  // N+1
    int*   cursor   = offsets + N_NODES + 1;            // N+1
    int*   gstart   = cursor + N_NODES + 1;             // 257
    int*   blocksum = gstart + N_GRAPHS + 1;            // SCAN_B
    int*   blockbase= blocksum + SCAN_B;                // SCAN_B
    uintptr_t wp = ((uintptr_t)(blockbase + SCAN_B) + 15) & ~(uintptr_t)15;
    uint2* rec = (uint2*)wp;                            // E * 8B
    unsigned short* xb  = (unsigned short*)(rec + N_EDGES);  // N*64 bf16
    unsigned short* h1b = xb + (long)N_NODES * 64;           // N*128 bf16
    unsigned short* h2b = h1b + (long)N_NODES * 128;         // N*128 bf16
    unsigned short* Bh1 = h2b + (long)N_NODES * 128;         // 128*128
    unsigned short* Bl1 = Bh1 + 128 * 128;
    unsigned short* Bh2 = Bl1 + 128 * 128;                   // 128*256
    unsigned short* Bl2 = Bh2 + 128 * 256;
    unsigned short* Bh3 = Bl2 + 128 * 256;                   // 128*128
    unsigned short* Bl3 = Bh3 + 128 * 128;
    // layer-3 outputs carved from agg2 region (free after GEMM2):
    unsigned short* y3b = (unsigned short*)agg2;             // N*64 bf16
    float* root3 = agg2 + (long)N_NODES * 64;                // N*64 f32
    float* h3    = agg1;                                     // N*64 f32

    const int gemm_grid = (N_NODES + 63) / 64;    // 782

    // ---- memset + fused prep (3x pack + cvt + count) ----
    hipMemsetAsync(count, 0, N_NODES * sizeof(int), stream);
    prep_kernel<<<6506, 256, 0, stream>>>(W1r, W1root, W2r, W2root, W3r, W3root,
                                          Bh1, Bl1, Bh2, Bl2, Bh3, Bl3,
                                          x, xb, ei, count);

    // ---- CSR build ----
    scan_blocks_kernel<<<SCAN_B, 256, 0, stream>>>(count, blocksum);
    scan_base_kernel<<<1, 256, 0, stream>>>(blocksum, blockbase);
    scan_final_kernel<<<SCAN_B + 1, 256, 0, stream>>>(count, blockbase, offsets, cursor,
                                                      batch, gstart);
    fill_kernel<<<2048, 256, 0, stream>>>(ei, ew, cursor, rec);

    // ---- layer 1: agg1 = gather(xb); h1b = bf16(tanh([agg1|xb]@B1 + b1)) ----
    gather_agg<64, false><<<(N_NODES + 31) / 32, 256, 0, stream>>>(xb, 64, offsets, rec, nullptr, agg1);
    gemm_mfma<64, 64, false, true><<<gemm_grid, 256, 0, stream>>>(
        agg1, 64, xb, 64, Bh1, Bl1, b1, h1b, nullptr);

    // ---- layer 2: agg2 = gather(h1b); h2b = bf16(tanh([agg2|h1b]@B2 + b2)) ----
    gather_agg<128, false><<<(N_NODES + 15) / 16, 256, 0, stream>>>(h1b, 128, offsets, rec, nullptr, agg2);
    gemm_mfma<128, 128, false, true><<<gemm_grid, 256, 0, stream>>>(
        agg2, 128, h1b, 128, Bh2, Bl2, b2, h2b, nullptr);

    // ---- layer 3: y3b = bf16(h2b@W3r^T); root3 = h2b@W3root^T + b3 ----
    gemm_mfma<0, 128, true, false><<<gemm_grid, 256, 0, stream>>>(
        nullptr, 0, h2b, 128, Bh3, Bl3, b3, y3b, root3);
    // fused: h3 = tanh(gather(y3b) + root3)
    gather_agg<64, true><<<(N_NODES + 31) / 32, 256, 0, stream>>>(y3b, 64, offsets, rec, root3, h3);

    // ---- fused pool + MLP ----
    pool_mlp_kernel<<<N_GRAPHS, 256, 0, stream>>>(h3, gstart, Wm1, bm1, Wm2, bm2, Wm3, bm3, out);
}